// Round 1
// 476.606 us; speedup vs baseline: 1.0626x; 1.0626x over previous
//
#include <hip/hip_runtime.h>
#include <cstdint>
#include <cstddef>

// ---------------------------------------------------------------------------
// GCN 2-layer encoder.  Pipeline per launch (12 dispatches):
//   1. bin_count: 782-bin histogram of dst>>7
//   2. bin_scan:  binStart/binCursor (fine) + superCursor (dst>>11, 49 bins)
//   3. super_fill: partition edges into super-bins, LDS tile staging
//   4. fine_fill:  scatter each super-segment into its 16 fine bins
//   5. node_count_dis: per-fine-bin LDS degree count -> count[], dis[]
//   6. bin_csr: per-bin LDS scan -> rowptr + col scatter
//   7. wsplit: W1/W2 -> transposed split-bf16 planes [2][64][K] (hi, lo)
//   8. gemm_mfma<256,false> -> h1 bf16 (MFMA, 3-term split-bf16 = fp32 acc)
//   9. agg1 -> out1 (bf16, relu)
//  10. gemm_mfma<64,true>  -> h2 bf16 (MFMA, 2-term: A exact bf16)
//  11. agg2 -> d_out (fp32)
// MFMA orientation: D[n][m] = Wt[n][k] * x[m][k]^T so each lane holds 4
// consecutive output cols of one node -> packs straight into uint2 bf16.
// ---------------------------------------------------------------------------

#define BIN_SHIFT 7
#define BIN_NODES 128
#define MAX_BINS 1024
#define SUP_SHIFT 11
#define FINE_PER_SUP 16
#define NSUP_MAX 64
#define SCAP 56  // per-super staging capacity per 2048-edge tile (mean 42)
#define SRC_BITS 17
#define SRC_MASK ((1 << SRC_BITS) - 1)

typedef unsigned short ushort_t;

typedef __attribute__((ext_vector_type(8))) short bf16x8;  // 8 bf16 (4 VGPRs)
typedef __attribute__((ext_vector_type(4))) float f32x4;   // MFMA accumulator

union FragB {
  uint4 u;
  bf16x8 b;
};

__device__ __forceinline__ float4 bfq2f4(uint2 p) {  // 4 packed bf16 -> fp32 (exact)
  float4 r;
  r.x = __uint_as_float(p.x << 16);
  r.y = __uint_as_float(p.x & 0xFFFF0000u);
  r.z = __uint_as_float(p.y << 16);
  r.w = __uint_as_float(p.y & 0xFFFF0000u);
  return r;
}
__device__ __forceinline__ unsigned f2bf(float f) {  // fp32 -> bf16 bits, RNE
  unsigned u = __float_as_uint(f);
  return (u + 0x7FFFu + ((u >> 16) & 1u)) >> 16;
}
__device__ __forceinline__ uint2 f42bfq(float4 f) {
  uint2 r;
  r.x = f2bf(f.x) | (f2bf(f.y) << 16);
  r.y = f2bf(f.z) | (f2bf(f.w) << 16);
  return r;
}

__global__ void zero_int(int* __restrict__ p, int n) {
  int i = blockIdx.x * blockDim.x + threadIdx.x;
  if (i < n) p[i] = 0;
}

// --- pass 1: fine histogram -------------------------------------------------
__global__ __launch_bounds__(256) void bin_count(const int* __restrict__ dst, int E, int nbins,
                                                 int* __restrict__ binCnt) {
  __shared__ int h[MAX_BINS];
  for (int i = threadIdx.x; i < nbins; i += 256) h[i] = 0;
  __syncthreads();
  int stride = gridDim.x * 256;
  for (int e = blockIdx.x * 256 + threadIdx.x; e < E; e += stride)
    atomicAdd(&h[dst[e] >> BIN_SHIFT], 1);
  __syncthreads();
  for (int i = threadIdx.x; i < nbins; i += 256)
    if (h[i]) atomicAdd(&binCnt[i], h[i]);
}

// --- pass 2: scan fine bins; derive super cursors ---------------------------
__global__ __launch_bounds__(256) void bin_scan(const int* __restrict__ binCnt, int nbins, int E,
                                                int* __restrict__ binStart,
                                                int* __restrict__ binCursor,
                                                int* __restrict__ supCursor) {
  __shared__ int s[256];
  int t = threadIdx.x;
  int c[4];
  int sum = 0;
#pragma unroll
  for (int i = 0; i < 4; i++) {
    int idx = t * 4 + i;
    c[i] = (idx < nbins) ? binCnt[idx] : 0;
    sum += c[i];
  }
  int v = sum;
  s[t] = v;
  __syncthreads();
  for (int d = 1; d < 256; d <<= 1) {
    int add = (t >= d) ? s[t - d] : 0;
    __syncthreads();
    s[t] += add;
    __syncthreads();
  }
  int run = s[t] - v;  // exclusive prefix
#pragma unroll
  for (int i = 0; i < 4; i++) {
    int idx = t * 4 + i;
    if (idx < nbins) {
      binStart[idx] = run;
      binCursor[idx] = run;
      if ((idx & (FINE_PER_SUP - 1)) == 0) supCursor[idx >> 4] = run;  // super segment start
      run += c[i];
    }
  }
  if (t == 0) binStart[nbins] = E;
}

// --- pass 3: partition into super-bins with LDS tile staging ----------------
__global__ __launch_bounds__(256) void super_fill(const int* __restrict__ src,
                                                  const int* __restrict__ dst, int E, int nsup,
                                                  int* __restrict__ supCursor,
                                                  unsigned* __restrict__ supbuf) {
  __shared__ unsigned stage[NSUP_MAX * SCAP];
  __shared__ int lcnt[NSUP_MAX], lbase[NSUP_MAX], lscan[NSUP_MAX + 1];
  int chunk = (E + gridDim.x - 1) / gridDim.x;
  int c0 = blockIdx.x * chunk;
  int c1 = min(E, c0 + chunk);
  for (int t0 = c0; t0 < c1; t0 += 2048) {
    int t1 = min(c1, t0 + 2048);
    if (threadIdx.x < nsup) lcnt[threadIdx.x] = 0;
    __syncthreads();
    for (int e = t0 + threadIdx.x; e < t1; e += 256) {
      int d = dst[e];
      int sb = d >> SUP_SHIFT;
      unsigned v = ((unsigned)(d & ((1 << SUP_SHIFT) - 1)) << SRC_BITS) | (unsigned)src[e];
      int idx = atomicAdd(&lcnt[sb], 1);
      if (idx < SCAP)
        stage[sb * SCAP + idx] = v;
      else {  // rare overflow: direct write
        int g = atomicAdd(&supCursor[sb], 1);
        supbuf[g] = v;
      }
    }
    __syncthreads();
    if (threadIdx.x < nsup) {
      int c = min(lcnt[threadIdx.x], SCAP);
      lcnt[threadIdx.x] = c;
      lbase[threadIdx.x] = c ? atomicAdd(&supCursor[threadIdx.x], c) : 0;
    }
    __syncthreads();
    if (threadIdx.x == 0) {  // tiny serial scan over <=64 bins
      int r = 0;
      for (int i = 0; i < nsup; i++) {
        lscan[i] = r;
        r += lcnt[i];
      }
      lscan[nsup] = r;
    }
    __syncthreads();
    int total = lscan[nsup];
    for (int j = threadIdx.x; j < total; j += 256) {
      int lo = 0, hi = nsup;  // binary search: lscan[lo] <= j < lscan[lo+1]
      while (hi - lo > 1) {
        int mid = (lo + hi) >> 1;
        if (lscan[mid] <= j)
          lo = mid;
        else
          hi = mid;
      }
      int off = j - lscan[lo];
      supbuf[lbase[lo] + off] = stage[lo * SCAP + off];
    }
    __syncthreads();
  }
}

// --- pass 4: scatter super-segment into its 16 fine bins (L2 window) --------
__global__ __launch_bounds__(256) void fine_fill(const unsigned* __restrict__ supbuf,
                                                 const int* __restrict__ binStart, int nbins,
                                                 int* __restrict__ binCursor,
                                                 unsigned* __restrict__ binbuf) {
  __shared__ int lcnt[FINE_PER_SUP], lbase[FINE_PER_SUP];
  int sb = blockIdx.x >> 3, p = blockIdx.x & 7;
  int seg0 = binStart[sb << 4];
  int seg1 = binStart[min((sb + 1) << 4, nbins)];
  int part = (seg1 - seg0 + 7) >> 3;
  int c0 = seg0 + p * part;
  int c1 = min(seg1, c0 + part);
  if (threadIdx.x < FINE_PER_SUP) lcnt[threadIdx.x] = 0;
  __syncthreads();
  for (int i = c0 + threadIdx.x; i < c1; i += 256) atomicAdd(&lcnt[supbuf[i] >> 24], 1);
  __syncthreads();
  if (threadIdx.x < FINE_PER_SUP) {
    int c = lcnt[threadIdx.x];
    lbase[threadIdx.x] = c ? atomicAdd(&binCursor[(sb << 4) + threadIdx.x], c) : 0;
    lcnt[threadIdx.x] = 0;
  }
  __syncthreads();
  for (int i = c0 + threadIdx.x; i < c1; i += 256) {
    unsigned v = supbuf[i];
    unsigned dls = v >> SRC_BITS;  // 11-bit dst-local-to-super
    int f = dls >> BIN_SHIFT;      // fine bin within super
    unsigned vf = ((dls & (BIN_NODES - 1)) << SRC_BITS) | (v & SRC_MASK);
    int idx = lbase[f] + atomicAdd(&lcnt[f], 1);
    binbuf[idx] = vf;
  }
}

// --- pass 5: per-bin node degree + dis --------------------------------------
__global__ __launch_bounds__(256) void node_count_dis(const unsigned* __restrict__ binbuf,
                                                      const int* __restrict__ binStart, int N,
                                                      int* __restrict__ count,
                                                      float* __restrict__ dis) {
  __shared__ int cnt[BIN_NODES];
  int b = blockIdx.x;
  int nodeBase = b << BIN_SHIFT;
  if (threadIdx.x < BIN_NODES) cnt[threadIdx.x] = 0;
  __syncthreads();
  int s0 = binStart[b], s1 = binStart[b + 1];
  for (int i = s0 + threadIdx.x; i < s1; i += 256) atomicAdd(&cnt[binbuf[i] >> SRC_BITS], 1);
  __syncthreads();
  if (threadIdx.x < BIN_NODES) {
    int node = nodeBase + threadIdx.x;
    if (node < N) {
      int c = cnt[threadIdx.x];
      count[node] = c;
      dis[node] = rsqrtf((float)(c + 1));  // +1 self loop
    }
  }
}

// --- pass 6: fused per-bin scan + CSR col scatter ---------------------------
__global__ __launch_bounds__(256) void bin_csr(const unsigned* __restrict__ binbuf,
                                               const int* __restrict__ binStart,
                                               const int* __restrict__ count, int N, int E,
                                               int* __restrict__ rowptr, int* __restrict__ col) {
  __shared__ int cur[BIN_NODES];
  __shared__ int pref[BIN_NODES];
  int b = blockIdx.x, t = threadIdx.x;
  int nodeBase = b << BIN_SHIFT;
  int c = 0;
  if (t < BIN_NODES) {
    int node = nodeBase + t;
    c = (node < N) ? count[node] : 0;
    pref[t] = c;
  }
  __syncthreads();
  for (int d = 1; d < BIN_NODES; d <<= 1) {  // inclusive scan over 128
    int add = (t < BIN_NODES && t >= d) ? pref[t - d] : 0;
    __syncthreads();
    if (t < BIN_NODES) pref[t] += add;
    __syncthreads();
  }
  int s0 = binStart[b];
  if (t < BIN_NODES) {
    int node = nodeBase + t;
    if (node < N) {
      int ex = s0 + pref[t] - c;  // exclusive prefix + segment base
      rowptr[node] = ex;
      cur[t] = ex;
    }
  }
  if (b == 0 && t == 255) rowptr[N] = E;
  __syncthreads();
  int s1 = binStart[b + 1];
  for (int i = s0 + t; i < s1; i += 256) {
    unsigned v = binbuf[i];
    int slot = atomicAdd(&cur[v >> SRC_BITS], 1);
    col[slot] = v & SRC_MASK;
  }
}

// --- pass 7: split W1/W2 into transposed bf16 hi/lo planes ------------------
// wt layout: [plane(hi=0,lo=1)][n(64)][k(K)] bf16.  hi = truncation,
// lo = bf16_trunc(w - hi_as_f32); hi+lo represents w to ~2^-16 relative.
__global__ __launch_bounds__(256) void wsplit(const float* __restrict__ W1,
                                              const float* __restrict__ W2,
                                              ushort_t* __restrict__ wt1,
                                              ushort_t* __restrict__ wt2) {
  int i = blockIdx.x * 256 + threadIdx.x;
  const float* W;
  ushort_t* wt;
  int K, idx;
  if (i < 256 * 64) {
    W = W1; wt = wt1; K = 256; idx = i;
  } else if (i < 256 * 64 + 64 * 64) {
    W = W2; wt = wt2; K = 64; idx = i - 256 * 64;
  } else
    return;
  int n = idx & 63, k = idx >> 6;
  float f = W[k * 64 + n];  // W is [K][64] row-major
  unsigned u = __float_as_uint(f);
  unsigned hb = u & 0xFFFF0000u;
  float lo = f - __uint_as_float(hb);
  wt[(size_t)n * K + k] = (ushort_t)(u >> 16);
  wt[(size_t)64 * K + (size_t)n * K + k] = (ushort_t)(__float_as_uint(lo) >> 16);
}

// split 8 consecutive fp32 into packed bf16 hi (truncate) + lo (truncate resid)
__device__ __forceinline__ void split8(const float* __restrict__ xp, uint4& xh, uint4& xl) {
  float f[8];
  *(float4*)&f[0] = *(const float4*)xp;
  *(float4*)&f[4] = *(const float4*)(xp + 4);
  unsigned hw[4], lw[4];
#pragma unroll
  for (int p = 0; p < 4; p++) {
    unsigned ua = __float_as_uint(f[2 * p]);
    unsigned ub = __float_as_uint(f[2 * p + 1]);
    unsigned ha = ua & 0xFFFF0000u;
    unsigned hb = ub & 0xFFFF0000u;
    float la = f[2 * p] - __uint_as_float(ha);
    float lb = f[2 * p + 1] - __uint_as_float(hb);
    hw[p] = (ua >> 16) | hb;
    lw[p] = (__float_as_uint(la) >> 16) | (__float_as_uint(lb) & 0xFFFF0000u);
  }
  xh = make_uint4(hw[0], hw[1], hw[2], hw[3]);
  xl = make_uint4(lw[0], lw[1], lw[2], lw[3]);
}

// --- MFMA GEMM: Cbf16[M][64] = A[M][K] @ W[K][64] ---------------------------
// Wt: pre-split transposed weights [2][64][K] bf16 (wsplit output).
// Orientation: D[n][m] with A-frag = Wt rows (n = lane&15, k = (lane>>4)*8+j
// contiguous) and B-frag = x rows (m = lane&15, same k window).  D gives each
// lane node m and 4 consecutive cols n = nt*16 + (lane>>4)*4 + r -> one uint2.
// ABF16=false: x fp32, 3-term split (xh*wh + xh*wl + xl*wh) ~= fp32 exact.
// ABF16=true:  A already bf16 (exact), 2-term (a*wh + a*wl).
// No LDS, no barriers; x read exactly once, coalesced 128B/row per k-tile.
template <int K, bool ABF16>
__global__ __launch_bounds__(256) void gemm_mfma(const void* __restrict__ Av,
                                                 const ushort_t* __restrict__ Wt,
                                                 uint2* __restrict__ Cb, int M) {
  const int lane = threadIdx.x & 63;
  const int wv = threadIdx.x >> 6;  // wave in block (4 waves)
  const int l15 = lane & 15;
  const int lq = lane >> 4;  // 0..3
  const int m0 = blockIdx.x * 128 + wv * 32;  // wave handles 32 nodes

  const ushort_t* __restrict__ Wlo = Wt + (size_t)64 * K;

  f32x4 acc[2][4];
#pragma unroll
  for (int a = 0; a < 2; a++)
#pragma unroll
    for (int b = 0; b < 4; b++) acc[a][b] = (f32x4){0.f, 0.f, 0.f, 0.f};

  int node[2], ncl[2];
#pragma unroll
  for (int mt = 0; mt < 2; mt++) {
    node[mt] = m0 + mt * 16 + l15;
    ncl[mt] = node[mt] < M ? node[mt] : (M - 1);
  }

#pragma unroll 2
  for (int kt = 0; kt < K / 32; kt++) {
    const int kb = kt * 32 + lq * 8;
    FragB wh[4], wl[4];
#pragma unroll
    for (int nt = 0; nt < 4; nt++) {
      wh[nt].u = *(const uint4*)(Wt + (size_t)(nt * 16 + l15) * K + kb);
      wl[nt].u = *(const uint4*)(Wlo + (size_t)(nt * 16 + l15) * K + kb);
    }
#pragma unroll
    for (int mt = 0; mt < 2; mt++) {
      if (ABF16) {
        FragB xa;
        xa.u = *(const uint4*)((const ushort_t*)Av + (size_t)ncl[mt] * K + kb);
#pragma unroll
        for (int nt = 0; nt < 4; nt++) {
          acc[mt][nt] =
              __builtin_amdgcn_mfma_f32_16x16x32_bf16(wh[nt].b, xa.b, acc[mt][nt], 0, 0, 0);
          acc[mt][nt] =
              __builtin_amdgcn_mfma_f32_16x16x32_bf16(wl[nt].b, xa.b, acc[mt][nt], 0, 0, 0);
        }
      } else {
        FragB xh, xl;
        split8((const float*)Av + (size_t)ncl[mt] * K + kb, xh.u, xl.u);
#pragma unroll
        for (int nt = 0; nt < 4; nt++) {
          acc[mt][nt] =
              __builtin_amdgcn_mfma_f32_16x16x32_bf16(wh[nt].b, xh.b, acc[mt][nt], 0, 0, 0);
          acc[mt][nt] =
              __builtin_amdgcn_mfma_f32_16x16x32_bf16(wl[nt].b, xh.b, acc[mt][nt], 0, 0, 0);
          acc[mt][nt] =
              __builtin_amdgcn_mfma_f32_16x16x32_bf16(wh[nt].b, xl.b, acc[mt][nt], 0, 0, 0);
        }
      }
    }
  }

#pragma unroll
  for (int mt = 0; mt < 2; mt++) {
    if (node[mt] < M) {
      uint2* cp = Cb + (size_t)node[mt] * 16 + lq;
#pragma unroll
      for (int nt = 0; nt < 4; nt++) {
        float4 o = make_float4(acc[mt][nt][0], acc[mt][nt][1], acc[mt][nt][2], acc[mt][nt][3]);
        cp[nt * 4] = f42bfq(o);  // cols nt*16 + lq*4 .. +3
      }
    }
  }
}

// --- aggregation: wave per node, 4 edges/wave, bf16 gather, on-the-fly w ----
// w_edge = dis[src]; final sum scaled by di = dis[dst] once:
//   out = di * ( sum_j dis[src_j]*h_j + di*h_self ) + bias
template <bool OUTBF>
__global__ __launch_bounds__(256) void agg_kernel(
    const uint2* __restrict__ h, const int* __restrict__ rowptr, const int* __restrict__ col,
    const float* __restrict__ dis, const float* __restrict__ bias, void* __restrict__ outv,
    int N, int relu) {
  int wid = (blockIdx.x * blockDim.x + threadIdx.x) >> 6;
  if (wid >= N) return;
  int lane = threadIdx.x & 63;
  int sub = lane & 15;
  int quarter = lane >> 4;

  int start = rowptr[wid], end = rowptr[wid + 1];
  float di = dis[wid];

  float4 a0 = make_float4(0.f, 0.f, 0.f, 0.f), a1 = a0, a2 = a0, a3 = a0;
  {  // self-loop: di*h_self (quarter 0 only); final *di makes it di^2
    float4 self = bfq2f4(h[(size_t)wid * 16 + sub]);
    if (quarter == 0) {
      a0.x = di * self.x;
      a0.y = di * self.y;
      a0.z = di * self.z;
      a0.w = di * self.w;
    }
  }

  for (int base = start; base < end; base += 64) {
    int e = base + lane;
    int sj = 0;
    float wj = 0.f;
    if (e < end) {
      sj = col[e];
      wj = dis[sj];  // L2-resident 400 KB table (replaces wgt stream)
    }
    int cnt = end - base;
    if (cnt > 64) cnt = 64;
    int rounds = (cnt + 3) >> 2;
    int t = 0;
    for (; t + 4 <= rounds; t += 4) {
      int i0 = 4 * t + quarter;
      int s0 = __shfl(sj, i0), s1 = __shfl(sj, i0 + 4), s2 = __shfl(sj, i0 + 8),
          s3 = __shfl(sj, i0 + 12);
      float w0 = __shfl(wj, i0), w1 = __shfl(wj, i0 + 4), w2 = __shfl(wj, i0 + 8),
            w3 = __shfl(wj, i0 + 12);
      float4 g0 = bfq2f4(h[(size_t)s0 * 16 + sub]);
      float4 g1 = bfq2f4(h[(size_t)s1 * 16 + sub]);
      float4 g2 = bfq2f4(h[(size_t)s2 * 16 + sub]);
      float4 g3 = bfq2f4(h[(size_t)s3 * 16 + sub]);
      a0.x += w0 * g0.x; a0.y += w0 * g0.y; a0.z += w0 * g0.z; a0.w += w0 * g0.w;
      a1.x += w1 * g1.x; a1.y += w1 * g1.y; a1.z += w1 * g1.z; a1.w += w1 * g1.w;
      a2.x += w2 * g2.x; a2.y += w2 * g2.y; a2.z += w2 * g2.z; a2.w += w2 * g2.w;
      a3.x += w3 * g3.x; a3.y += w3 * g3.y; a3.z += w3 * g3.z; a3.w += w3 * g3.w;
    }
    for (; t < rounds; t++) {
      int i0 = 4 * t + quarter;  // tail quarters past cnt have wj==0
      int s0 = __shfl(sj, i0);
      float w0 = __shfl(wj, i0);
      float4 g0 = bfq2f4(h[(size_t)s0 * 16 + sub]);
      a0.x += w0 * g0.x; a0.y += w0 * g0.y; a0.z += w0 * g0.z; a0.w += w0 * g0.w;
    }
  }

  float sx = (a0.x + a1.x) + (a2.x + a3.x);
  float sy = (a0.y + a1.y) + (a2.y + a3.y);
  float sz = (a0.z + a1.z) + (a2.z + a3.z);
  float sw = (a0.w + a1.w) + (a2.w + a3.w);
  sx += __shfl_down(sx, 32); sy += __shfl_down(sy, 32);
  sz += __shfl_down(sz, 32); sw += __shfl_down(sw, 32);
  sx += __shfl_down(sx, 16); sy += __shfl_down(sy, 16);
  sz += __shfl_down(sz, 16); sw += __shfl_down(sw, 16);
  if (quarter == 0) {
    float4 bv = ((const float4*)bias)[sub];
    float4 o = make_float4(di * sx + bv.x, di * sy + bv.y, di * sz + bv.z, di * sw + bv.w);
    if (relu) {
      o.x = fmaxf(o.x, 0.f);
      o.y = fmaxf(o.y, 0.f);
      o.z = fmaxf(o.z, 0.f);
      o.w = fmaxf(o.w, 0.f);
    }
    if (OUTBF)
      ((uint2*)outv)[(size_t)wid * 16 + sub] = f42bfq(o);
    else
      ((float4*)outv)[(size_t)wid * 16 + sub] = o;
  }
}

// ---------------------------------------------------------------------------
extern "C" void kernel_launch(void* const* d_in, const int* in_sizes, int n_in,
                              void* d_out, int out_size, void* d_ws, size_t ws_size,
                              hipStream_t stream) {
  const float* x = (const float*)d_in[0];
  const int* ei = (const int*)d_in[1];
  const float* W1 = (const float*)d_in[2];
  const float* b1 = (const float*)d_in[3];
  const float* W2 = (const float*)d_in[4];
  const float* b2 = (const float*)d_in[5];

  const int IN = 256;
  const int E = in_sizes[1] / 2;
  const int N = in_sizes[0] / IN;
  const int* src = ei;
  const int* dst = ei + E;
  const int nbins = (N + BIN_NODES - 1) >> BIN_SHIFT;
  const int nsup = (N + (1 << SUP_SHIFT) - 1) >> SUP_SHIFT;

  // workspace carve-up (256B aligned)
  char* ws = (char*)d_ws;
  size_t off = 0;
  auto alloc = [&](size_t bytes) -> void* {
    void* p = ws + off;
    off += (bytes + 255) & ~(size_t)255;
    return p;
  };
  int* count = (int*)alloc((size_t)N * 4);
  int* rowptr = (int*)alloc((size_t)(N + 1) * 4);
  float* dis = (float*)alloc((size_t)N * 4);
  int* binCnt = (int*)alloc(MAX_BINS * 4);
  int* binStart = (int*)alloc((MAX_BINS + 1) * 4);
  int* binCursor = (int*)alloc(MAX_BINS * 4);
  int* supCursor = (int*)alloc(NSUP_MAX * 4);
  int* col = (int*)alloc((size_t)E * 4);                // 12.8 MB; written by bin_csr
  unsigned* supbuf = (unsigned*)col;                    // alias: dead before col written
  uint2* out1 = (uint2*)alloc((size_t)N * 64 * 2);      // bf16 layer-1 activations
  size_t big = ((size_t)E * 4 > (size_t)N * 128) ? (size_t)E * 4 : (size_t)N * 128;
  unsigned* binbuf = (unsigned*)alloc(big);             // aliases h (dead before gemm1)
  uint2* h = (uint2*)binbuf;
  ushort_t* wt1 = (ushort_t*)alloc((size_t)2 * 64 * 256 * 2);  // 64 KB split W1
  ushort_t* wt2 = (ushort_t*)alloc((size_t)2 * 64 * 64 * 2);   // 16 KB split W2
  float* outf = (float*)d_out;

  zero_int<<<(nbins + 255) / 256, 256, 0, stream>>>(binCnt, nbins);
  bin_count<<<1024, 256, 0, stream>>>(dst, E, nbins, binCnt);
  bin_scan<<<1, 256, 0, stream>>>(binCnt, nbins, E, binStart, binCursor, supCursor);
  super_fill<<<512, 256, 0, stream>>>(src, dst, E, nsup, supCursor, supbuf);
  fine_fill<<<nsup * 8, 256, 0, stream>>>(supbuf, binStart, nbins, binCursor, binbuf);
  node_count_dis<<<nbins, 256, 0, stream>>>(binbuf, binStart, N, count, dis);
  bin_csr<<<nbins, 256, 0, stream>>>(binbuf, binStart, count, N, E, rowptr, col);
  wsplit<<<(256 * 64 + 64 * 64 + 255) / 256, 256, 0, stream>>>(W1, W2, wt1, wt2);

  gemm_mfma<256, false><<<(N + 127) / 128, 256, 0, stream>>>(x, wt1, h, N);
  agg_kernel<true><<<(N + 3) / 4, 256, 0, stream>>>(h, rowptr, col, dis, b1, out1, N, 1);
  gemm_mfma<64, true><<<(N + 127) / 128, 256, 0, stream>>>(out1, wt2, h, N);
  agg_kernel<false><<<(N + 3) / 4, 256, 0, stream>>>(h, rowptr, col, dis, b2, outf, N, 0);
}

// Round 3
// 473.944 us; speedup vs baseline: 1.0686x; 1.0056x over previous
//
#include <hip/hip_runtime.h>
#include <cstdint>
#include <cstddef>

// ---------------------------------------------------------------------------
// GCN 2-layer encoder.  Pipeline per launch (12 dispatches):
//   1. bin_count: 782-bin histogram of dst>>7
//   2. bin_scan:  binStart/binCursor (fine) + superCursor (dst>>11, 49 bins)
//   3. super_fill: partition edges into super-bins, LDS tile staging
//   4. fine_fill:  scatter each super-segment into its 16 fine bins
//   5. node_count_dis: per-fine-bin LDS degree count -> count[], dis[]
//   6. bin_csr: per-bin LDS scan -> rowptr + col scatter
//   7. wsplit: W1/W2 -> transposed split-bf16 planes [2][64][K] (hi, lo)
//   8. gemm_mfma<256,false> -> h1 bf16 (MFMA, 3-term split-bf16 = fp32 acc)
//      software-pipelined: wh prefetch depth 1, x prefetch depth 2 (vmcnt
//      FIFO-safe issue order: w before x within an iteration)
//   9. agg1 -> out1 (bf16, relu)
//  10. gemm_mfma<64,true>  -> h2 bf16 (MFMA, 2-term: A exact bf16)
//  11. agg2 -> d_out (fp32)
// MFMA orientation: D[n][m] = Wt[n][k] * x[m][k]^T so each lane holds 4
// consecutive output cols of one node -> packs straight into uint2 bf16.
// ---------------------------------------------------------------------------

#define BIN_SHIFT 7
#define BIN_NODES 128
#define MAX_BINS 1024
#define SUP_SHIFT 11
#define FINE_PER_SUP 16
#define NSUP_MAX 64
#define SCAP 56  // per-super staging capacity per 2048-edge tile (mean 42)
#define SRC_BITS 17
#define SRC_MASK ((1 << SRC_BITS) - 1)

typedef unsigned short ushort_t;

typedef __attribute__((ext_vector_type(8))) short bf16x8;  // 8 bf16 (4 VGPRs)
typedef __attribute__((ext_vector_type(4))) float f32x4;   // MFMA accumulator

union FragB {
  uint4 u;
  bf16x8 b;
};

__device__ __forceinline__ float4 bfq2f4(uint2 p) {  // 4 packed bf16 -> fp32 (exact)
  float4 r;
  r.x = __uint_as_float(p.x << 16);
  r.y = __uint_as_float(p.x & 0xFFFF0000u);
  r.z = __uint_as_float(p.y << 16);
  r.w = __uint_as_float(p.y & 0xFFFF0000u);
  return r;
}
__device__ __forceinline__ unsigned f2bf(float f) {  // fp32 -> bf16 bits, RNE
  unsigned u = __float_as_uint(f);
  return (u + 0x7FFFu + ((u >> 16) & 1u)) >> 16;
}
__device__ __forceinline__ uint2 f42bfq(float4 f) {
  uint2 r;
  r.x = f2bf(f.x) | (f2bf(f.y) << 16);
  r.y = f2bf(f.z) | (f2bf(f.w) << 16);
  return r;
}

__global__ void zero_int(int* __restrict__ p, int n) {
  int i = blockIdx.x * blockDim.x + threadIdx.x;
  if (i < n) p[i] = 0;
}

// --- pass 1: fine histogram -------------------------------------------------
__global__ __launch_bounds__(256) void bin_count(const int* __restrict__ dst, int E, int nbins,
                                                 int* __restrict__ binCnt) {
  __shared__ int h[MAX_BINS];
  for (int i = threadIdx.x; i < nbins; i += 256) h[i] = 0;
  __syncthreads();
  int stride = gridDim.x * 256;
  for (int e = blockIdx.x * 256 + threadIdx.x; e < E; e += stride)
    atomicAdd(&h[dst[e] >> BIN_SHIFT], 1);
  __syncthreads();
  for (int i = threadIdx.x; i < nbins; i += 256)
    if (h[i]) atomicAdd(&binCnt[i], h[i]);
}

// --- pass 2: scan fine bins; derive super cursors ---------------------------
__global__ __launch_bounds__(256) void bin_scan(const int* __restrict__ binCnt, int nbins, int E,
                                                int* __restrict__ binStart,
                                                int* __restrict__ binCursor,
                                                int* __restrict__ supCursor) {
  __shared__ int s[256];
  int t = threadIdx.x;
  int c[4];
  int sum = 0;
#pragma unroll
  for (int i = 0; i < 4; i++) {
    int idx = t * 4 + i;
    c[i] = (idx < nbins) ? binCnt[idx] : 0;
    sum += c[i];
  }
  int v = sum;
  s[t] = v;
  __syncthreads();
  for (int d = 1; d < 256; d <<= 1) {
    int add = (t >= d) ? s[t - d] : 0;
    __syncthreads();
    s[t] += add;
    __syncthreads();
  }
  int run = s[t] - v;  // exclusive prefix
#pragma unroll
  for (int i = 0; i < 4; i++) {
    int idx = t * 4 + i;
    if (idx < nbins) {
      binStart[idx] = run;
      binCursor[idx] = run;
      if ((idx & (FINE_PER_SUP - 1)) == 0) supCursor[idx >> 4] = run;  // super segment start
      run += c[i];
    }
  }
  if (t == 0) binStart[nbins] = E;
}

// --- pass 3: partition into super-bins with LDS tile staging ----------------
__global__ __launch_bounds__(256) void super_fill(const int* __restrict__ src,
                                                  const int* __restrict__ dst, int E, int nsup,
                                                  int* __restrict__ supCursor,
                                                  unsigned* __restrict__ supbuf) {
  __shared__ unsigned stage[NSUP_MAX * SCAP];
  __shared__ int lcnt[NSUP_MAX], lbase[NSUP_MAX], lscan[NSUP_MAX + 1];
  int chunk = (E + gridDim.x - 1) / gridDim.x;
  int c0 = blockIdx.x * chunk;
  int c1 = min(E, c0 + chunk);
  for (int t0 = c0; t0 < c1; t0 += 2048) {
    int t1 = min(c1, t0 + 2048);
    if (threadIdx.x < nsup) lcnt[threadIdx.x] = 0;
    __syncthreads();
    for (int e = t0 + threadIdx.x; e < t1; e += 256) {
      int d = dst[e];
      int sb = d >> SUP_SHIFT;
      unsigned v = ((unsigned)(d & ((1 << SUP_SHIFT) - 1)) << SRC_BITS) | (unsigned)src[e];
      int idx = atomicAdd(&lcnt[sb], 1);
      if (idx < SCAP)
        stage[sb * SCAP + idx] = v;
      else {  // rare overflow: direct write
        int g = atomicAdd(&supCursor[sb], 1);
        supbuf[g] = v;
      }
    }
    __syncthreads();
    if (threadIdx.x < nsup) {
      int c = min(lcnt[threadIdx.x], SCAP);
      lcnt[threadIdx.x] = c;
      lbase[threadIdx.x] = c ? atomicAdd(&supCursor[threadIdx.x], c) : 0;
    }
    __syncthreads();
    if (threadIdx.x == 0) {  // tiny serial scan over <=64 bins
      int r = 0;
      for (int i = 0; i < nsup; i++) {
        lscan[i] = r;
        r += lcnt[i];
      }
      lscan[nsup] = r;
    }
    __syncthreads();
    int total = lscan[nsup];
    for (int j = threadIdx.x; j < total; j += 256) {
      int lo = 0, hi = nsup;  // binary search: lscan[lo] <= j < lscan[lo+1]
      while (hi - lo > 1) {
        int mid = (lo + hi) >> 1;
        if (lscan[mid] <= j)
          lo = mid;
        else
          hi = mid;
      }
      int off = j - lscan[lo];
      supbuf[lbase[lo] + off] = stage[lo * SCAP + off];
    }
    __syncthreads();
  }
}

// --- pass 4: scatter super-segment into its 16 fine bins (L2 window) --------
__global__ __launch_bounds__(256) void fine_fill(const unsigned* __restrict__ supbuf,
                                                 const int* __restrict__ binStart, int nbins,
                                                 int* __restrict__ binCursor,
                                                 unsigned* __restrict__ binbuf) {
  __shared__ int lcnt[FINE_PER_SUP], lbase[FINE_PER_SUP];
  int sb = blockIdx.x >> 3, p = blockIdx.x & 7;
  int seg0 = binStart[sb << 4];
  int seg1 = binStart[min((sb + 1) << 4, nbins)];
  int part = (seg1 - seg0 + 7) >> 3;
  int c0 = seg0 + p * part;
  int c1 = min(seg1, c0 + part);
  if (threadIdx.x < FINE_PER_SUP) lcnt[threadIdx.x] = 0;
  __syncthreads();
  for (int i = c0 + threadIdx.x; i < c1; i += 256) atomicAdd(&lcnt[supbuf[i] >> 24], 1);
  __syncthreads();
  if (threadIdx.x < FINE_PER_SUP) {
    int c = lcnt[threadIdx.x];
    lbase[threadIdx.x] = c ? atomicAdd(&binCursor[(sb << 4) + threadIdx.x], c) : 0;
    lcnt[threadIdx.x] = 0;
  }
  __syncthreads();
  for (int i = c0 + threadIdx.x; i < c1; i += 256) {
    unsigned v = supbuf[i];
    unsigned dls = v >> SRC_BITS;  // 11-bit dst-local-to-super
    int f = dls >> BIN_SHIFT;      // fine bin within super
    unsigned vf = ((dls & (BIN_NODES - 1)) << SRC_BITS) | (v & SRC_MASK);
    int idx = lbase[f] + atomicAdd(&lcnt[f], 1);
    binbuf[idx] = vf;
  }
}

// --- pass 5: per-bin node degree + dis --------------------------------------
__global__ __launch_bounds__(256) void node_count_dis(const unsigned* __restrict__ binbuf,
                                                      const int* __restrict__ binStart, int N,
                                                      int* __restrict__ count,
                                                      float* __restrict__ dis) {
  __shared__ int cnt[BIN_NODES];
  int b = blockIdx.x;
  int nodeBase = b << BIN_SHIFT;
  if (threadIdx.x < BIN_NODES) cnt[threadIdx.x] = 0;
  __syncthreads();
  int s0 = binStart[b], s1 = binStart[b + 1];
  for (int i = s0 + threadIdx.x; i < s1; i += 256) atomicAdd(&cnt[binbuf[i] >> SRC_BITS], 1);
  __syncthreads();
  if (threadIdx.x < BIN_NODES) {
    int node = nodeBase + threadIdx.x;
    if (node < N) {
      int c = cnt[threadIdx.x];
      count[node] = c;
      dis[node] = rsqrtf((float)(c + 1));  // +1 self loop
    }
  }
}

// --- pass 6: fused per-bin scan + CSR col scatter ---------------------------
__global__ __launch_bounds__(256) void bin_csr(const unsigned* __restrict__ binbuf,
                                               const int* __restrict__ binStart,
                                               const int* __restrict__ count, int N, int E,
                                               int* __restrict__ rowptr, int* __restrict__ col) {
  __shared__ int cur[BIN_NODES];
  __shared__ int pref[BIN_NODES];
  int b = blockIdx.x, t = threadIdx.x;
  int nodeBase = b << BIN_SHIFT;
  int c = 0;
  if (t < BIN_NODES) {
    int node = nodeBase + t;
    c = (node < N) ? count[node] : 0;
    pref[t] = c;
  }
  __syncthreads();
  for (int d = 1; d < BIN_NODES; d <<= 1) {  // inclusive scan over 128
    int add = (t < BIN_NODES && t >= d) ? pref[t - d] : 0;
    __syncthreads();
    if (t < BIN_NODES) pref[t] += add;
    __syncthreads();
  }
  int s0 = binStart[b];
  if (t < BIN_NODES) {
    int node = nodeBase + t;
    if (node < N) {
      int ex = s0 + pref[t] - c;  // exclusive prefix + segment base
      rowptr[node] = ex;
      cur[t] = ex;
    }
  }
  if (b == 0 && t == 255) rowptr[N] = E;
  __syncthreads();
  int s1 = binStart[b + 1];
  for (int i = s0 + t; i < s1; i += 256) {
    unsigned v = binbuf[i];
    int slot = atomicAdd(&cur[v >> SRC_BITS], 1);
    col[slot] = v & SRC_MASK;
  }
}

// --- pass 7: split W1/W2 into transposed bf16 hi/lo planes ------------------
// wt layout: [plane(hi=0,lo=1)][n(64)][k(K)] bf16.  hi = truncation,
// lo = bf16_trunc(w - hi_as_f32); hi+lo represents w to ~2^-16 relative.
__global__ __launch_bounds__(256) void wsplit(const float* __restrict__ W1,
                                              const float* __restrict__ W2,
                                              ushort_t* __restrict__ wt1,
                                              ushort_t* __restrict__ wt2) {
  int i = blockIdx.x * 256 + threadIdx.x;
  const float* W;
  ushort_t* wt;
  int K, idx;
  if (i < 256 * 64) {
    W = W1; wt = wt1; K = 256; idx = i;
  } else if (i < 256 * 64 + 64 * 64) {
    W = W2; wt = wt2; K = 64; idx = i - 256 * 64;
  } else
    return;
  int n = idx & 63, k = idx >> 6;
  float f = W[k * 64 + n];  // W is [K][64] row-major
  unsigned u = __float_as_uint(f);
  unsigned hb = u & 0xFFFF0000u;
  float lo = f - __uint_as_float(hb);
  wt[(size_t)n * K + k] = (ushort_t)(u >> 16);
  wt[(size_t)64 * K + (size_t)n * K + k] = (ushort_t)(__float_as_uint(lo) >> 16);
}

// split 8 packed fp32 (as 2 uint4) into bf16 hi (truncate) + lo (trunc resid)
__device__ __forceinline__ void split8u(uint4 a, uint4 b, uint4& xh, uint4& xl) {
  unsigned ua[8] = {a.x, a.y, a.z, a.w, b.x, b.y, b.z, b.w};
  unsigned hw[4], lw[4];
#pragma unroll
  for (int p = 0; p < 4; p++) {
    unsigned u0 = ua[2 * p], u1 = ua[2 * p + 1];
    unsigned h0 = u0 & 0xFFFF0000u, h1 = u1 & 0xFFFF0000u;
    float l0 = __uint_as_float(u0) - __uint_as_float(h0);
    float l1 = __uint_as_float(u1) - __uint_as_float(h1);
    hw[p] = (u0 >> 16) | h1;
    lw[p] = (__float_as_uint(l0) >> 16) | (__float_as_uint(l1) & 0xFFFF0000u);
  }
  xh = make_uint4(hw[0], hw[1], hw[2], hw[3]);
  xl = make_uint4(lw[0], lw[1], lw[2], lw[3]);
}

// --- MFMA GEMM: Cbf16[M][64] = A[M][K] @ W[K][64] ---------------------------
// Wt: pre-split transposed weights [2][64][K] bf16 (wsplit output).
// Orientation: D[n][m], A-frag = Wt rows, B-frag = x rows (see header).
// K=256 fp32 path: software pipeline.  Issue order per iter (vmcnt FIFO-safe):
//   wh[kt+1] -> wl[kt] -> (copy x[kt] regs) -> issue x[kt+2] -> split+MFMA.
// Consumes never drain a younger prefetch that is needed later than 1 iter.
// K=64 bf16 path: all 20 loads issued up front, two wait points.
template <int K, bool ABF16>
__global__ __launch_bounds__(256, 3) void gemm_mfma(const void* __restrict__ Av,
                                                    const ushort_t* __restrict__ Wt,
                                                    uint2* __restrict__ Cb, int M) {
  const int lane = threadIdx.x & 63;
  const int wv = threadIdx.x >> 6;  // wave in block (4 waves)
  const int l15 = lane & 15;
  const int lq = lane >> 4;                   // 0..3
  const int m0 = blockIdx.x * 128 + wv * 32;  // wave handles 32 nodes

  const ushort_t* __restrict__ Wlo = Wt + (size_t)64 * K;

  f32x4 acc[2][4];
#pragma unroll
  for (int a = 0; a < 2; a++)
#pragma unroll
    for (int b = 0; b < 4; b++) acc[a][b] = (f32x4){0.f, 0.f, 0.f, 0.f};

  int node[2], ncl[2];
#pragma unroll
  for (int mt = 0; mt < 2; mt++) {
    node[mt] = m0 + mt * 16 + l15;
    ncl[mt] = node[mt] < M ? node[mt] : (M - 1);
  }

  if (ABF16) {
    // ---- K=64 bf16 path: 2 tiles, fully hoisted loads -----------------------
    constexpr int NT = K / 32;
    FragB xa[NT][2], wh[NT][4], wl[NT][4];
#pragma unroll
    for (int t = 0; t < NT; t++)
#pragma unroll
      for (int mt = 0; mt < 2; mt++)
        xa[t][mt].u = *(const uint4*)((const ushort_t*)Av + (size_t)ncl[mt] * K + t * 32 + lq * 8);
#pragma unroll
    for (int t = 0; t < NT; t++)
#pragma unroll
      for (int nt = 0; nt < 4; nt++) {
        wh[t][nt].u = *(const uint4*)(Wt + (size_t)(nt * 16 + l15) * K + t * 32 + lq * 8);
        wl[t][nt].u = *(const uint4*)(Wlo + (size_t)(nt * 16 + l15) * K + t * 32 + lq * 8);
      }
#pragma unroll
    for (int t = 0; t < NT; t++)
#pragma unroll
      for (int mt = 0; mt < 2; mt++)
#pragma unroll
        for (int nt = 0; nt < 4; nt++) {
          acc[mt][nt] =
              __builtin_amdgcn_mfma_f32_16x16x32_bf16(wh[t][nt].b, xa[t][mt].b, acc[mt][nt], 0, 0, 0);
          acc[mt][nt] =
              __builtin_amdgcn_mfma_f32_16x16x32_bf16(wl[t][nt].b, xa[t][mt].b, acc[mt][nt], 0, 0, 0);
        }
  } else {
    // ---- K=256 fp32 path: pipelined (wh depth 1, x depth 2, wl in-iter) -----
    constexpr int NT = K / 32;  // 8
    const float* __restrict__ A = (const float*)Av;
    uint4 xp[2][2][2];  // [slot = kt&1][mt][half]
    FragB wh[2][4];     // [slot = kt&1][nt]
    FragB wlc[4];       // current tile only

    // prologue: wh[0], then x[0], x[1]
#pragma unroll
    for (int nt = 0; nt < 4; nt++)
      wh[0][nt].u = *(const uint4*)(Wt + (size_t)(nt * 16 + l15) * K + lq * 8);
#pragma unroll
    for (int t = 0; t < 2; t++)
#pragma unroll
      for (int mt = 0; mt < 2; mt++) {
        const float* p = A + (size_t)ncl[mt] * K + t * 32 + lq * 8;
        xp[t][mt][0] = *(const uint4*)p;
        xp[t][mt][1] = *(const uint4*)(p + 4);
      }

#pragma unroll
    for (int kt = 0; kt < NT; kt++) {
      const int cs = kt & 1;
      const int kb = kt * 32 + lq * 8;
      // 1. issue next wh tile (prefetch depth 1)
      if (kt + 1 < NT) {
        const int kbn = (kt + 1) * 32 + lq * 8;
#pragma unroll
        for (int nt = 0; nt < 4; nt++)
          wh[cs ^ 1][nt].u = *(const uint4*)(Wt + (size_t)(nt * 16 + l15) * K + kbn);
      }
      // 2. issue current wl tile (consumed last in this iter)
#pragma unroll
      for (int nt = 0; nt < 4; nt++)
        wlc[nt].u = *(const uint4*)(Wlo + (size_t)(nt * 16 + l15) * K + kb);
      // 3. pull current x into locals (wait lands here; x[kt] is oldest in queue)
      uint4 c0a = xp[cs][0][0], c0b = xp[cs][0][1];
      uint4 c1a = xp[cs][1][0], c1b = xp[cs][1][1];
      // 4. issue x tile kt+2 into the freed slot
      if (kt + 2 < NT) {
#pragma unroll
        for (int mt = 0; mt < 2; mt++) {
          const float* p = A + (size_t)ncl[mt] * K + (kt + 2) * 32 + lq * 8;
          xp[cs][mt][0] = *(const uint4*)p;
          xp[cs][mt][1] = *(const uint4*)(p + 4);
        }
      }
      // 5. split + MFMA (wh terms first, wl term last)
      FragB xh0, xl0, xh1, xl1;
      split8u(c0a, c0b, xh0.u, xl0.u);
      split8u(c1a, c1b, xh1.u, xl1.u);
#pragma unroll
      for (int nt = 0; nt < 4; nt++) {
        acc[0][nt] = __builtin_amdgcn_mfma_f32_16x16x32_bf16(wh[cs][nt].b, xh0.b, acc[0][nt], 0, 0, 0);
        acc[0][nt] = __builtin_amdgcn_mfma_f32_16x16x32_bf16(wh[cs][nt].b, xl0.b, acc[0][nt], 0, 0, 0);
        acc[1][nt] = __builtin_amdgcn_mfma_f32_16x16x32_bf16(wh[cs][nt].b, xh1.b, acc[1][nt], 0, 0, 0);
        acc[1][nt] = __builtin_amdgcn_mfma_f32_16x16x32_bf16(wh[cs][nt].b, xl1.b, acc[1][nt], 0, 0, 0);
      }
#pragma unroll
      for (int nt = 0; nt < 4; nt++) {
        acc[0][nt] = __builtin_amdgcn_mfma_f32_16x16x32_bf16(wlc[nt].b, xh0.b, acc[0][nt], 0, 0, 0);
        acc[1][nt] = __builtin_amdgcn_mfma_f32_16x16x32_bf16(wlc[nt].b, xh1.b, acc[1][nt], 0, 0, 0);
      }
    }
  }

#pragma unroll
  for (int mt = 0; mt < 2; mt++) {
    if (node[mt] < M) {
      uint2* cp = Cb + (size_t)node[mt] * 16 + lq;
#pragma unroll
      for (int nt = 0; nt < 4; nt++) {
        float4 o = make_float4(acc[mt][nt][0], acc[mt][nt][1], acc[mt][nt][2], acc[mt][nt][3]);
        cp[nt * 4] = f42bfq(o);  // cols nt*16 + lq*4 .. +3
      }
    }
  }
}

// --- aggregation: wave per node, 4 edges/wave, bf16 gather, on-the-fly w ----
// w_edge = dis[src]; final sum scaled by di = dis[dst] once:
//   out = di * ( sum_j dis[src_j]*h_j + di*h_self ) + bias
template <bool OUTBF>
__global__ __launch_bounds__(256) void agg_kernel(
    const uint2* __restrict__ h, const int* __restrict__ rowptr, const int* __restrict__ col,
    const float* __restrict__ dis, const float* __restrict__ bias, void* __restrict__ outv,
    int N, int relu) {
  int wid = (blockIdx.x * blockDim.x + threadIdx.x) >> 6;
  if (wid >= N) return;
  int lane = threadIdx.x & 63;
  int sub = lane & 15;
  int quarter = lane >> 4;

  int start = rowptr[wid], end = rowptr[wid + 1];
  float di = dis[wid];

  float4 a0 = make_float4(0.f, 0.f, 0.f, 0.f), a1 = a0, a2 = a0, a3 = a0;
  {  // self-loop: di*h_self (quarter 0 only); final *di makes it di^2
    float4 self = bfq2f4(h[(size_t)wid * 16 + sub]);
    if (quarter == 0) {
      a0.x = di * self.x;
      a0.y = di * self.y;
      a0.z = di * self.z;
      a0.w = di * self.w;
    }
  }

  for (int base = start; base < end; base += 64) {
    int e = base + lane;
    int sj = 0;
    float wj = 0.f;
    if (e < end) {
      sj = col[e];
      wj = dis[sj];  // L2-resident 400 KB table (replaces wgt stream)
    }
    int cnt = end - base;
    if (cnt > 64) cnt = 64;
    int rounds = (cnt + 3) >> 2;
    int t = 0;
    for (; t + 4 <= rounds; t += 4) {
      int i0 = 4 * t + quarter;
      int s0 = __shfl(sj, i0), s1 = __shfl(sj, i0 + 4), s2 = __shfl(sj, i0 + 8),
          s3 = __shfl(sj, i0 + 12);
      float w0 = __shfl(wj, i0), w1 = __shfl(wj, i0 + 4), w2 = __shfl(wj, i0 + 8),
            w3 = __shfl(wj, i0 + 12);
      float4 g0 = bfq2f4(h[(size_t)s0 * 16 + sub]);
      float4 g1 = bfq2f4(h[(size_t)s1 * 16 + sub]);
      float4 g2 = bfq2f4(h[(size_t)s2 * 16 + sub]);
      float4 g3 = bfq2f4(h[(size_t)s3 * 16 + sub]);
      a0.x += w0 * g0.x; a0.y += w0 * g0.y; a0.z += w0 * g0.z; a0.w += w0 * g0.w;
      a1.x += w1 * g1.x; a1.y += w1 * g1.y; a1.z += w1 * g1.z; a1.w += w1 * g1.w;
      a2.x += w2 * g2.x; a2.y += w2 * g2.y; a2.z += w2 * g2.z; a2.w += w2 * g2.w;
      a3.x += w3 * g3.x; a3.y += w3 * g3.y; a3.z += w3 * g3.z; a3.w += w3 * g3.w;
    }
    for (; t < rounds; t++) {
      int i0 = 4 * t + quarter;  // tail quarters past cnt have wj==0
      int s0 = __shfl(sj, i0);
      float w0 = __shfl(wj, i0);
      float4 g0 = bfq2f4(h[(size_t)s0 * 16 + sub]);
      a0.x += w0 * g0.x; a0.y += w0 * g0.y; a0.z += w0 * g0.z; a0.w += w0 * g0.w;
    }
  }

  float sx = (a0.x + a1.x) + (a2.x + a3.x);
  float sy = (a0.y + a1.y) + (a2.y + a3.y);
  float sz = (a0.z + a1.z) + (a2.z + a3.z);
  float sw = (a0.w + a1.w) + (a2.w + a3.w);
  sx += __shfl_down(sx, 32); sy += __shfl_down(sy, 32);
  sz += __shfl_down(sz, 32); sw += __shfl_down(sw, 32);
  sx += __shfl_down(sx, 16); sy += __shfl_down(sy, 16);
  sz += __shfl_down(sz, 16); sw += __shfl_down(sw, 16);
  if (quarter == 0) {
    float4 bv = ((const float4*)bias)[sub];
    float4 o = make_float4(di * sx + bv.x, di * sy + bv.y, di * sz + bv.z, di * sw + bv.w);
    if (relu) {
      o.x = fmaxf(o.x, 0.f);
      o.y = fmaxf(o.y, 0.f);
      o.z = fmaxf(o.z, 0.f);
      o.w = fmaxf(o.w, 0.f);
    }
    if (OUTBF)
      ((uint2*)outv)[(size_t)wid * 16 + sub] = f42bfq(o);
    else
      ((float4*)outv)[(size_t)wid * 16 + sub] = o;
  }
}

// ---------------------------------------------------------------------------
extern "C" void kernel_launch(void* const* d_in, const int* in_sizes, int n_in,
                              void* d_out, int out_size, void* d_ws, size_t ws_size,
                              hipStream_t stream) {
  const float* x = (const float*)d_in[0];
  const int* ei = (const int*)d_in[1];
  const float* W1 = (const float*)d_in[2];
  const float* b1 = (const float*)d_in[3];
  const float* W2 = (const float*)d_in[4];
  const float* b2 = (const float*)d_in[5];

  const int IN = 256;
  const int E = in_sizes[1] / 2;
  const int N = in_sizes[0] / IN;
  const int* src = ei;
  const int* dst = ei + E;
  const int nbins = (N + BIN_NODES - 1) >> BIN_SHIFT;
  const int nsup = (N + (1 << SUP_SHIFT) - 1) >> SUP_SHIFT;

  // workspace carve-up (256B aligned)
  char* ws = (char*)d_ws;
  size_t off = 0;
  auto alloc = [&](size_t bytes) -> void* {
    void* p = ws + off;
    off += (bytes + 255) & ~(size_t)255;
    return p;
  };
  int* count = (int*)alloc((size_t)N * 4);
  int* rowptr = (int*)alloc((size_t)(N + 1) * 4);
  float* dis = (float*)alloc((size_t)N * 4);
  int* binCnt = (int*)alloc(MAX_BINS * 4);
  int* binStart = (int*)alloc((MAX_BINS + 1) * 4);
  int* binCursor = (int*)alloc(MAX_BINS * 4);
  int* supCursor = (int*)alloc(NSUP_MAX * 4);
  int* col = (int*)alloc((size_t)E * 4);                // 12.8 MB; written by bin_csr
  unsigned* supbuf = (unsigned*)col;                    // alias: dead before col written
  uint2* out1 = (uint2*)alloc((size_t)N * 64 * 2);      // bf16 layer-1 activations
  size_t big = ((size_t)E * 4 > (size_t)N * 128) ? (size_t)E * 4 : (size_t)N * 128;
  unsigned* binbuf = (unsigned*)alloc(big);             // aliases h (dead before gemm1)
  uint2* h = (uint2*)binbuf;
  ushort_t* wt1 = (ushort_t*)alloc((size_t)2 * 64 * 256 * 2);  // 64 KB split W1
  ushort_t* wt2 = (ushort_t*)alloc((size_t)2 * 64 * 64 * 2);   // 16 KB split W2
  float* outf = (float*)d_out;

  zero_int<<<(nbins + 255) / 256, 256, 0, stream>>>(binCnt, nbins);
  bin_count<<<1024, 256, 0, stream>>>(dst, E, nbins, binCnt);
  bin_scan<<<1, 256, 0, stream>>>(binCnt, nbins, E, binStart, binCursor, supCursor);
  super_fill<<<512, 256, 0, stream>>>(src, dst, E, nsup, supCursor, supbuf);
  fine_fill<<<nsup * 8, 256, 0, stream>>>(supbuf, binStart, nbins, binCursor, binbuf);
  node_count_dis<<<nbins, 256, 0, stream>>>(binbuf, binStart, N, count, dis);
  bin_csr<<<nbins, 256, 0, stream>>>(binbuf, binStart, count, N, E, rowptr, col);
  wsplit<<<(256 * 64 + 64 * 64 + 255) / 256, 256, 0, stream>>>(W1, W2, wt1, wt2);

  gemm_mfma<256, false><<<(N + 127) / 128, 256, 0, stream>>>(x, wt1, h, N);
  agg_kernel<true><<<(N + 3) / 4, 256, 0, stream>>>(h, rowptr, col, dis, b1, out1, N, 1);
  gemm_mfma<64, true><<<(N + 127) / 128, 256, 0, stream>>>(out1, wt2, h, N);
  agg_kernel<false><<<(N + 3) / 4, 256, 0, stream>>>(h, rowptr, col, dis, b2, outf, N, 0);
}

// Round 5
// 463.627 us; speedup vs baseline: 1.0924x; 1.0223x over previous
//
#include <hip/hip_runtime.h>
#include <cstdint>
#include <cstddef>

// ---------------------------------------------------------------------------
// GCN 2-layer encoder.  Pipeline per launch (12 dispatches):
//   1. bin_count: 782-bin histogram of dst>>7
//   2. bin_scan:  binStart/binCursor (fine) + superCursor (dst>>11, 49 bins)
//   3. super_fill: partition edges into super-bins (1 tile/block, reg-prefetch,
//      wave-parallel scan)
//   4. fine_fill:  scatter each super-segment into its 16 fine bins
//   5. node_count_dis: per-fine-bin LDS degree count -> count[], dis[]
//   6. bin_csr: per-bin LDS scan -> rowptr + col scatter
//   7. wsplit: W1/W2 -> transposed split-bf16 planes [2][64][K] (hi, lo)
//   8. gemm1_mfma -> h1 bf16: per-wave LDS-DMA pipelined split-bf16 MFMA.
//      x staged via global_load_lds (width 16) into a 3-buffer ring, XOR-
//      swizzled source so linear DMA dest + swizzled ds_read_b128 is
//      conflict-minimal.  Weights reg-pipelined depth-1; issue order pinned
//      with sched_barrier so compiler weight-waits never drain the x queue.
//      No barriers: each wave stages only the rows it reads.
//   9. agg1 -> out1 (bf16, relu)
//  10. gemm2_mfma -> h2 bf16 (A exact bf16, 2-term)
//  11. agg2 -> d_out (fp32)
// MFMA orientation: D[n][m] = Wt[n][k] * x[m][k]^T so each lane holds 4
// consecutive output cols of one node -> packs straight into uint2 bf16.
// ---------------------------------------------------------------------------

#define BIN_SHIFT 7
#define BIN_NODES 128
#define MAX_BINS 1024
#define SUP_SHIFT 11
#define FINE_PER_SUP 16
#define NSUP_MAX 64
#define SCAP 56  // per-super staging capacity per 2048-edge tile (mean 42)
#define SRC_BITS 17
#define SRC_MASK ((1 << SRC_BITS) - 1)

typedef unsigned short ushort_t;

typedef __attribute__((ext_vector_type(8))) short bf16x8;  // 8 bf16 (4 VGPRs)
typedef __attribute__((ext_vector_type(4))) float f32x4;   // MFMA accumulator

union FragB {
  uint4 u;
  bf16x8 b;
};

__device__ __forceinline__ float4 bfq2f4(uint2 p) {  // 4 packed bf16 -> fp32 (exact)
  float4 r;
  r.x = __uint_as_float(p.x << 16);
  r.y = __uint_as_float(p.x & 0xFFFF0000u);
  r.z = __uint_as_float(p.y << 16);
  r.w = __uint_as_float(p.y & 0xFFFF0000u);
  return r;
}
__device__ __forceinline__ unsigned f2bf(float f) {  // fp32 -> bf16 bits, RNE
  unsigned u = __float_as_uint(f);
  return (u + 0x7FFFu + ((u >> 16) & 1u)) >> 16;
}
__device__ __forceinline__ uint2 f42bfq(float4 f) {
  uint2 r;
  r.x = f2bf(f.x) | (f2bf(f.y) << 16);
  r.y = f2bf(f.z) | (f2bf(f.w) << 16);
  return r;
}

__global__ void zero_int(int* __restrict__ p, int n) {
  int i = blockIdx.x * blockDim.x + threadIdx.x;
  if (i < n) p[i] = 0;
}

// --- pass 1: fine histogram -------------------------------------------------
__global__ __launch_bounds__(256) void bin_count(const int* __restrict__ dst, int E, int nbins,
                                                 int* __restrict__ binCnt) {
  __shared__ int h[MAX_BINS];
  for (int i = threadIdx.x; i < nbins; i += 256) h[i] = 0;
  __syncthreads();
  int stride = gridDim.x * 256;
  for (int e = blockIdx.x * 256 + threadIdx.x; e < E; e += stride)
    atomicAdd(&h[dst[e] >> BIN_SHIFT], 1);
  __syncthreads();
  for (int i = threadIdx.x; i < nbins; i += 256)
    if (h[i]) atomicAdd(&binCnt[i], h[i]);
}

// --- pass 2: scan fine bins; derive super cursors ---------------------------
__global__ __launch_bounds__(256) void bin_scan(const int* __restrict__ binCnt, int nbins, int E,
                                                int* __restrict__ binStart,
                                                int* __restrict__ binCursor,
                                                int* __restrict__ supCursor) {
  __shared__ int s[256];
  int t = threadIdx.x;
  int c[4];
  int sum = 0;
#pragma unroll
  for (int i = 0; i < 4; i++) {
    int idx = t * 4 + i;
    c[i] = (idx < nbins) ? binCnt[idx] : 0;
    sum += c[i];
  }
  int v = sum;
  s[t] = v;
  __syncthreads();
  for (int d = 1; d < 256; d <<= 1) {
    int add = (t >= d) ? s[t - d] : 0;
    __syncthreads();
    s[t] += add;
    __syncthreads();
  }
  int run = s[t] - v;  // exclusive prefix
#pragma unroll
  for (int i = 0; i < 4; i++) {
    int idx = t * 4 + i;
    if (idx < nbins) {
      binStart[idx] = run;
      binCursor[idx] = run;
      if ((idx & (FINE_PER_SUP - 1)) == 0) supCursor[idx >> 4] = run;  // super segment start
      run += c[i];
    }
  }
  if (t == 0) binStart[nbins] = E;
}

// --- pass 3: partition into super-bins, one 2048-edge tile per block --------
// Register-prefetch all 8 edge pairs (16 loads in flight) before the LDS
// atomic phase; wave-0 shfl scan replaces the serial thread-0 scan.
__global__ __launch_bounds__(256) void super_fill(const int* __restrict__ src,
                                                  const int* __restrict__ dst, int E, int nsup,
                                                  int* __restrict__ supCursor,
                                                  unsigned* __restrict__ supbuf) {
  __shared__ unsigned stage[NSUP_MAX * SCAP];
  __shared__ int lcnt[NSUP_MAX], lbase[NSUP_MAX], lscan[NSUP_MAX + 1];
  const int tid = threadIdx.x;
  const int t0 = blockIdx.x * 2048;
  const int t1 = min(E, t0 + 2048);

  int dv[8], sv[8];
#pragma unroll
  for (int i = 0; i < 8; i++) {
    int e = t0 + i * 256 + tid;
    if (e < t1) {
      dv[i] = dst[e];
      sv[i] = src[e];
    }
  }
  if (tid < nsup) lcnt[tid] = 0;
  __syncthreads();
#pragma unroll
  for (int i = 0; i < 8; i++) {
    int e = t0 + i * 256 + tid;
    if (e < t1) {
      int d = dv[i];
      int sb = d >> SUP_SHIFT;
      unsigned v = ((unsigned)(d & ((1 << SUP_SHIFT) - 1)) << SRC_BITS) | (unsigned)sv[i];
      int idx = atomicAdd(&lcnt[sb], 1);
      if (idx < SCAP)
        stage[sb * SCAP + idx] = v;
      else {  // rare overflow: direct write
        int g = atomicAdd(&supCursor[sb], 1);
        supbuf[g] = v;
      }
    }
  }
  __syncthreads();
  if (tid < nsup) {
    int c = min(lcnt[tid], SCAP);
    lcnt[tid] = c;
    lbase[tid] = c ? atomicAdd(&supCursor[tid], c) : 0;
  }
  __syncthreads();
  if (tid < 64) {  // wave-0 inclusive scan over 64 bins
    int vv = (tid < nsup) ? lcnt[tid] : 0;
    int ss = vv;
#pragma unroll
    for (int d = 1; d < 64; d <<= 1) {
      int u = __shfl_up(ss, d);
      if (tid >= d) ss += u;
    }
    lscan[tid + 1] = ss;
    if (tid == 0) lscan[0] = 0;
  }
  __syncthreads();
  int total = lscan[nsup];
  for (int j = tid; j < total; j += 256) {
    int lo = 0, hi = nsup;  // binary search: lscan[lo] <= j < lscan[lo+1]
    while (hi - lo > 1) {
      int mid = (lo + hi) >> 1;
      if (lscan[mid] <= j)
        lo = mid;
      else
        hi = mid;
    }
    int off = j - lscan[lo];
    supbuf[lbase[lo] + off] = stage[lo * SCAP + off];
  }
}

// --- pass 4: scatter super-segment into its 16 fine bins (L2 window) --------
__global__ __launch_bounds__(256) void fine_fill(const unsigned* __restrict__ supbuf,
                                                 const int* __restrict__ binStart, int nbins,
                                                 int* __restrict__ binCursor,
                                                 unsigned* __restrict__ binbuf) {
  __shared__ int lcnt[FINE_PER_SUP], lbase[FINE_PER_SUP];
  int sb = blockIdx.x >> 3, p = blockIdx.x & 7;
  int seg0 = binStart[sb << 4];
  int seg1 = binStart[min((sb + 1) << 4, nbins)];
  int part = (seg1 - seg0 + 7) >> 3;
  int c0 = seg0 + p * part;
  int c1 = min(seg1, c0 + part);
  if (threadIdx.x < FINE_PER_SUP) lcnt[threadIdx.x] = 0;
  __syncthreads();
  for (int i = c0 + threadIdx.x; i < c1; i += 256) atomicAdd(&lcnt[supbuf[i] >> 24], 1);
  __syncthreads();
  if (threadIdx.x < FINE_PER_SUP) {
    int c = lcnt[threadIdx.x];
    lbase[threadIdx.x] = c ? atomicAdd(&binCursor[(sb << 4) + threadIdx.x], c) : 0;
    lcnt[threadIdx.x] = 0;
  }
  __syncthreads();
  for (int i = c0 + threadIdx.x; i < c1; i += 256) {
    unsigned v = supbuf[i];
    unsigned dls = v >> SRC_BITS;  // 11-bit dst-local-to-super
    int f = dls >> BIN_SHIFT;      // fine bin within super
    unsigned vf = ((dls & (BIN_NODES - 1)) << SRC_BITS) | (v & SRC_MASK);
    int idx = lbase[f] + atomicAdd(&lcnt[f], 1);
    binbuf[idx] = vf;
  }
}

// --- pass 5: per-bin node degree + dis --------------------------------------
__global__ __launch_bounds__(256) void node_count_dis(const unsigned* __restrict__ binbuf,
                                                      const int* __restrict__ binStart, int N,
                                                      int* __restrict__ count,
                                                      float* __restrict__ dis) {
  __shared__ int cnt[BIN_NODES];
  int b = blockIdx.x;
  int nodeBase = b << BIN_SHIFT;
  if (threadIdx.x < BIN_NODES) cnt[threadIdx.x] = 0;
  __syncthreads();
  int s0 = binStart[b], s1 = binStart[b + 1];
  for (int i = s0 + threadIdx.x; i < s1; i += 256) atomicAdd(&cnt[binbuf[i] >> SRC_BITS], 1);
  __syncthreads();
  if (threadIdx.x < BIN_NODES) {
    int node = nodeBase + threadIdx.x;
    if (node < N) {
      int c = cnt[threadIdx.x];
      count[node] = c;
      dis[node] = rsqrtf((float)(c + 1));  // +1 self loop
    }
  }
}

// --- pass 6: fused per-bin scan + CSR col scatter ---------------------------
__global__ __launch_bounds__(256) void bin_csr(const unsigned* __restrict__ binbuf,
                                               const int* __restrict__ binStart,
                                               const int* __restrict__ count, int N, int E,
                                               int* __restrict__ rowptr, int* __restrict__ col) {
  __shared__ int cur[BIN_NODES];
  __shared__ int pref[BIN_NODES];
  int b = blockIdx.x, t = threadIdx.x;
  int nodeBase = b << BIN_SHIFT;
  int c = 0;
  if (t < BIN_NODES) {
    int node = nodeBase + t;
    c = (node < N) ? count[node] : 0;
    pref[t] = c;
  }
  __syncthreads();
  for (int d = 1; d < BIN_NODES; d <<= 1) {  // inclusive scan over 128
    int add = (t < BIN_NODES && t >= d) ? pref[t - d] : 0;
    __syncthreads();
    if (t < BIN_NODES) pref[t] += add;
    __syncthreads();
  }
  int s0 = binStart[b];
  if (t < BIN_NODES) {
    int node = nodeBase + t;
    if (node < N) {
      int ex = s0 + pref[t] - c;  // exclusive prefix + segment base
      rowptr[node] = ex;
      cur[t] = ex;
    }
  }
  if (b == 0 && t == 255) rowptr[N] = E;
  __syncthreads();
  int s1 = binStart[b + 1];
  for (int i = s0 + t; i < s1; i += 256) {
    unsigned v = binbuf[i];
    int slot = atomicAdd(&cur[v >> SRC_BITS], 1);
    col[slot] = v & SRC_MASK;
  }
}

// --- pass 7: split W1/W2 into transposed bf16 hi/lo planes ------------------
__global__ __launch_bounds__(256) void wsplit(const float* __restrict__ W1,
                                              const float* __restrict__ W2,
                                              ushort_t* __restrict__ wt1,
                                              ushort_t* __restrict__ wt2) {
  int i = blockIdx.x * 256 + threadIdx.x;
  const float* W;
  ushort_t* wt;
  int K, idx;
  if (i < 256 * 64) {
    W = W1; wt = wt1; K = 256; idx = i;
  } else if (i < 256 * 64 + 64 * 64) {
    W = W2; wt = wt2; K = 64; idx = i - 256 * 64;
  } else
    return;
  int n = idx & 63, k = idx >> 6;
  float f = W[k * 64 + n];  // W is [K][64] row-major
  unsigned u = __float_as_uint(f);
  unsigned hb = u & 0xFFFF0000u;
  float lo = f - __uint_as_float(hb);
  wt[(size_t)n * K + k] = (ushort_t)(u >> 16);
  wt[(size_t)64 * K + (size_t)n * K + k] = (ushort_t)(__float_as_uint(lo) >> 16);
}

// split 8 packed fp32 (as 2 uint4) into bf16 hi (truncate) + lo (trunc resid)
__device__ __forceinline__ void split8u(uint4 a, uint4 b, uint4& xh, uint4& xl) {
  unsigned ua[8] = {a.x, a.y, a.z, a.w, b.x, b.y, b.z, b.w};
  unsigned hw[4], lw[4];
#pragma unroll
  for (int p = 0; p < 4; p++) {
    unsigned u0 = ua[2 * p], u1 = ua[2 * p + 1];
    unsigned h0 = u0 & 0xFFFF0000u, h1 = u1 & 0xFFFF0000u;
    float l0 = __uint_as_float(u0) - __uint_as_float(h0);
    float l1 = __uint_as_float(u1) - __uint_as_float(h1);
    hw[p] = (u0 >> 16) | h1;
    lw[p] = (__float_as_uint(l0) >> 16) | (__float_as_uint(l1) & 0xFFFF0000u);
  }
  xh = make_uint4(hw[0], hw[1], hw[2], hw[3]);
  xl = make_uint4(lw[0], lw[1], lw[2], lw[3]);
}

// --- gemm1: Cbf16[M][64] = x[M][256] @ W1, per-wave LDS-DMA pipeline --------
// Each wave owns 32 nodes; per 32-wide k-tile it DMAs its 32 rows (4 KB) into
// its slice of a 3-buffer LDS ring via global_load_lds (4 calls x 1 KB).
// Source addresses are XOR-swizzled (c4 ^= r&7) so the linear DMA dest plus
// swizzled ds_read_b128 has minimal bank aliasing.  Weights are depth-1
// register-pipelined and ISSUED BEFORE each stage call (sched_barrier-pinned),
// so the compiler's weight-wait (vmcnt) always leaves the x-DMA queue intact.
// Steady-state queue entering iter j: [st(j) 4, w(j) 8, st(j+1) 4] = 16;
// explicit vmcnt(12) drains exactly st(j) -> tile j staged before ds_read.
// Tail (j=7): queue [st(7) 4, w(7) 8] -> vmcnt(8).  No __syncthreads at all.
__global__ __launch_bounds__(256, 3) void gemm1_mfma(const float* __restrict__ A,
                                                     const ushort_t* __restrict__ Wt,
                                                     uint2* __restrict__ Cb, int M) {
  constexpr int K = 256;
  __shared__ uint4 xtile[3][4][256];  // [ring buf][wave][slot] = 48 KB
  const int lane = threadIdx.x & 63;
  const int wv = threadIdx.x >> 6;
  const int l15 = lane & 15;
  const int lq = lane >> 4;
  const int m0 = blockIdx.x * 128 + wv * 32;

  const ushort_t* __restrict__ Wlo = Wt + (size_t)64 * K;

  f32x4 acc[2][4];
#pragma unroll
  for (int a = 0; a < 2; a++)
#pragma unroll
    for (int b = 0; b < 4; b++) acc[a][b] = (f32x4){0.f, 0.f, 0.f, 0.f};

  // stage tile kt into ring buffer buf (this wave's 32 rows, 4 KB, 4 DMA calls)
  auto stage_tile = [&](int kt, int buf) {
#pragma unroll
    for (int c = 0; c < 4; c++) {
      int s = c * 64 + lane;
      int r = s >> 3;                 // row 0..31 within wave block
      int c4 = (s & 7) ^ (r & 7);     // swizzled float4-column
      int nd = m0 + r;
      if (nd >= M) nd = M - 1;
      const float* gp = A + (size_t)nd * K + kt * 32 + c4 * 4;
      __builtin_amdgcn_global_load_lds(
          (const __attribute__((address_space(1))) void*)gp,
          (__attribute__((address_space(3))) void*)&xtile[buf][wv][c * 64], 16, 0, 0);
    }
  };
  // load weight tile kt (hi 4 + lo 4) into wr[0..7]
  auto load_w = [&](int kt, FragB* wr) {
    const int kb = kt * 32 + lq * 8;
#pragma unroll
    for (int nt = 0; nt < 4; nt++) {
      wr[nt].u = *(const uint4*)(Wt + (size_t)(nt * 16 + l15) * K + kb);
      wr[4 + nt].u = *(const uint4*)(Wlo + (size_t)(nt * 16 + l15) * K + kb);
    }
  };

  FragB w[2][8];
  // prologue: st(0), w(0), st(1)  -> queue [st0 4, w0 8, st1 4]
  stage_tile(0, 0);
  load_w(0, w[0]);
  __builtin_amdgcn_sched_barrier(0);
  stage_tile(1, 1);
  __builtin_amdgcn_sched_barrier(0);

#pragma unroll
  for (int j = 0; j < 8; j++) {
    // a. ensure tile j staged (drain exactly st(j); keep w(j) + st(j+1))
    if (j < 7)
      asm volatile("s_waitcnt vmcnt(12)" ::: "memory");
    else
      asm volatile("s_waitcnt vmcnt(8)" ::: "memory");
    __builtin_amdgcn_sched_barrier(0);
    // b. ds_read tile j fragments (swizzled)
    uint4 xa[2][2];
#pragma unroll
    for (int mt = 0; mt < 2; mt++) {
      int mr = mt * 16 + l15;
#pragma unroll
      for (int hh = 0; hh < 2; hh++) {
        int c4 = (lq * 2 + hh) ^ (mr & 7);
        xa[mt][hh] = *(const uint4*)&xtile[j % 3][wv][mr * 8 + c4];
      }
    }
    // c. issue next weight tile (older than the next stage call)
    if (j + 1 < 8) load_w(j + 1, w[(j + 1) & 1]);
    __builtin_amdgcn_sched_barrier(0);
    // d. issue stage for tile j+2
    if (j + 2 < 8) stage_tile(j + 2, (j + 2) % 3);
    __builtin_amdgcn_sched_barrier(0);
    // e. split + MFMA (compiler weight-wait leaves st(j+1), st(j+2) in flight)
    FragB xh0, xl0, xh1, xl1;
    split8u(xa[0][0], xa[0][1], xh0.u, xl0.u);
    split8u(xa[1][0], xa[1][1], xh1.u, xl1.u);
    const FragB* wc = w[j & 1];
#pragma unroll
    for (int nt = 0; nt < 4; nt++) {
      acc[0][nt] = __builtin_amdgcn_mfma_f32_16x16x32_bf16(wc[nt].b, xh0.b, acc[0][nt], 0, 0, 0);
      acc[0][nt] = __builtin_amdgcn_mfma_f32_16x16x32_bf16(wc[nt].b, xl0.b, acc[0][nt], 0, 0, 0);
      acc[1][nt] = __builtin_amdgcn_mfma_f32_16x16x32_bf16(wc[nt].b, xh1.b, acc[1][nt], 0, 0, 0);
      acc[1][nt] = __builtin_amdgcn_mfma_f32_16x16x32_bf16(wc[nt].b, xl1.b, acc[1][nt], 0, 0, 0);
    }
#pragma unroll
    for (int nt = 0; nt < 4; nt++) {
      acc[0][nt] = __builtin_amdgcn_mfma_f32_16x16x32_bf16(wc[4 + nt].b, xh0.b, acc[0][nt], 0, 0, 0);
      acc[1][nt] = __builtin_amdgcn_mfma_f32_16x16x32_bf16(wc[4 + nt].b, xh1.b, acc[1][nt], 0, 0, 0);
    }
  }

#pragma unroll
  for (int mt = 0; mt < 2; mt++) {
    int node = m0 + mt * 16 + l15;
    if (node < M) {
      uint2* cp = Cb + (size_t)node * 16 + lq;
#pragma unroll
      for (int nt = 0; nt < 4; nt++) {
        float4 o = make_float4(acc[mt][nt][0], acc[mt][nt][1], acc[mt][nt][2], acc[mt][nt][3]);
        cp[nt * 4] = f42bfq(o);  // cols nt*16 + lq*4 .. +3
      }
    }
  }
}

// --- gemm2: Cbf16[M][64] = out1[M][64] @ W2 (A exact bf16, 2-term) ----------
__global__ __launch_bounds__(256, 3) void gemm2_mfma(const ushort_t* __restrict__ Av,
                                                     const ushort_t* __restrict__ Wt,
                                                     uint2* __restrict__ Cb, int M) {
  constexpr int K = 64;
  constexpr int NT = K / 32;  // 2
  const int lane = threadIdx.x & 63;
  const int wv = threadIdx.x >> 6;
  const int l15 = lane & 15;
  const int lq = lane >> 4;
  const int m0 = blockIdx.x * 128 + wv * 32;

  const ushort_t* __restrict__ Wlo = Wt + (size_t)64 * K;

  f32x4 acc[2][4];
#pragma unroll
  for (int a = 0; a < 2; a++)
#pragma unroll
    for (int b = 0; b < 4; b++) acc[a][b] = (f32x4){0.f, 0.f, 0.f, 0.f};

  int node[2], ncl[2];
#pragma unroll
  for (int mt = 0; mt < 2; mt++) {
    node[mt] = m0 + mt * 16 + l15;
    ncl[mt] = node[mt] < M ? node[mt] : (M - 1);
  }

  FragB xa[NT][2], wh[NT][4], wl[NT][4];
#pragma unroll
  for (int t = 0; t < NT; t++)
#pragma unroll
    for (int mt = 0; mt < 2; mt++)
      xa[t][mt].u = *(const uint4*)(Av + (size_t)ncl[mt] * K + t * 32 + lq * 8);
#pragma unroll
  for (int t = 0; t < NT; t++)
#pragma unroll
    for (int nt = 0; nt < 4; nt++) {
      wh[t][nt].u = *(const uint4*)(Wt + (size_t)(nt * 16 + l15) * K + t * 32 + lq * 8);
      wl[t][nt].u = *(const uint4*)(Wlo + (size_t)(nt * 16 + l15) * K + t * 32 + lq * 8);
    }
#pragma unroll
  for (int t = 0; t < NT; t++)
#pragma unroll
    for (int mt = 0; mt < 2; mt++)
#pragma unroll
      for (int nt = 0; nt < 4; nt++) {
        acc[mt][nt] =
            __builtin_amdgcn_mfma_f32_16x16x32_bf16(wh[t][nt].b, xa[t][mt].b, acc[mt][nt], 0, 0, 0);
        acc[mt][nt] =
            __builtin_amdgcn_mfma_f32_16x16x32_bf16(wl[t][nt].b, xa[t][mt].b, acc[mt][nt], 0, 0, 0);
      }

#pragma unroll
  for (int mt = 0; mt < 2; mt++) {
    if (node[mt] < M) {
      uint2* cp = Cb + (size_t)node[mt] * 16 + lq;
#pragma unroll
      for (int nt = 0; nt < 4; nt++) {
        float4 o = make_float4(acc[mt][nt][0], acc[mt][nt][1], acc[mt][nt][2], acc[mt][nt][3]);
        cp[nt * 4] = f42bfq(o);
      }
    }
  }
}

// --- aggregation: wave per node, 4 edges/wave, bf16 gather, on-the-fly w ----
template <bool OUTBF>
__global__ __launch_bounds__(256) void agg_kernel(
    const uint2* __restrict__ h, const int* __restrict__ rowptr, const int* __restrict__ col,
    const float* __restrict__ dis, const float* __restrict__ bias, void* __restrict__ outv,
    int N, int relu) {
  int wid = (blockIdx.x * blockDim.x + threadIdx.x) >> 6;
  if (wid >= N) return;
  int lane = threadIdx.x & 63;
  int sub = lane & 15;
  int quarter = lane >> 4;

  int start = rowptr[wid], end = rowptr[wid + 1];
  float di = dis[wid];

  float4 a0 = make_float4(0.f, 0.f, 0.f, 0.f), a1 = a0, a2 = a0, a3 = a0;
  {  // self-loop: di*h_self (quarter 0 only); final *di makes it di^2
    float4 self = bfq2f4(h[(size_t)wid * 16 + sub]);
    if (quarter == 0) {
      a0.x = di * self.x;
      a0.y = di * self.y;
      a0.z = di * self.z;
      a0.w = di * self.w;
    }
  }

  for (int base = start; base < end; base += 64) {
    int e = base + lane;
    int sj = 0;
    float wj = 0.f;
    if (e < end) {
      sj = col[e];
      wj = dis[sj];  // L2-resident 400 KB table (replaces wgt stream)
    }
    int cnt = end - base;
    if (cnt > 64) cnt = 64;
    int rounds = (cnt + 3) >> 2;
    int t = 0;
    for (; t + 4 <= rounds; t += 4) {
      int i0 = 4 * t + quarter;
      int s0 = __shfl(sj, i0), s1 = __shfl(sj, i0 + 4), s2 = __shfl(sj, i0 + 8),
          s3 = __shfl(sj, i0 + 12);
      float w0 = __shfl(wj, i0), w1 = __shfl(wj, i0 + 4), w2 = __shfl(wj, i0 + 8),
            w3 = __shfl(wj, i0 + 12);
      float4 g0 = bfq2f4(h[(size_t)s0 * 16 + sub]);
      float4 g1 = bfq2f4(h[(size_t)s1 * 16 + sub]);
      float4 g2 = bfq2f4(h[(size_t)s2 * 16 + sub]);
      float4 g3 = bfq2f4(h[(size_t)s3 * 16 + sub]);
      a0.x += w0 * g0.x; a0.y += w0 * g0.y; a0.z += w0 * g0.z; a0.w += w0 * g0.w;
      a1.x += w1 * g1.x; a1.y += w1 * g1.y; a1.z += w1 * g1.z; a1.w += w1 * g1.w;
      a2.x += w2 * g2.x; a2.y += w2 * g2.y; a2.z += w2 * g2.z; a2.w += w2 * g2.w;
      a3.x += w3 * g3.x; a3.y += w3 * g3.y; a3.z += w3 * g3.z; a3.w += w3 * g3.w;
    }
    for (; t < rounds; t++) {
      int i0 = 4 * t + quarter;  // tail quarters past cnt have wj==0
      int s0 = __shfl(sj, i0);
      float w0 = __shfl(wj, i0);
      float4 g0 = bfq2f4(h[(size_t)s0 * 16 + sub]);
      a0.x += w0 * g0.x; a0.y += w0 * g0.y; a0.z += w0 * g0.z; a0.w += w0 * g0.w;
    }
  }

  float sx = (a0.x + a1.x) + (a2.x + a3.x);
  float sy = (a0.y + a1.y) + (a2.y + a3.y);
  float sz = (a0.z + a1.z) + (a2.z + a3.z);
  float sw = (a0.w + a1.w) + (a2.w + a3.w);
  sx += __shfl_down(sx, 32); sy += __shfl_down(sy, 32);
  sz += __shfl_down(sz, 32); sw += __shfl_down(sw, 32);
  sx += __shfl_down(sx, 16); sy += __shfl_down(sy, 16);
  sz += __shfl_down(sz, 16); sw += __shfl_down(sw, 16);
  if (quarter == 0) {
    float4 bv = ((const float4*)bias)[sub];
    float4 o = make_float4(di * sx + bv.x, di * sy + bv.y, di * sz + bv.z, di * sw + bv.w);
    if (relu) {
      o.x = fmaxf(o.x, 0.f);
      o.y = fmaxf(o.y, 0.f);
      o.z = fmaxf(o.z, 0.f);
      o.w = fmaxf(o.w, 0.f);
    }
    if (OUTBF)
      ((uint2*)outv)[(size_t)wid * 16 + sub] = f42bfq(o);
    else
      ((float4*)outv)[(size_t)wid * 16 + sub] = o;
  }
}

// ---------------------------------------------------------------------------
extern "C" void kernel_launch(void* const* d_in, const int* in_sizes, int n_in,
                              void* d_out, int out_size, void* d_ws, size_t ws_size,
                              hipStream_t stream) {
  const float* x = (const float*)d_in[0];
  const int* ei = (const int*)d_in[1];
  const float* W1 = (const float*)d_in[2];
  const float* b1 = (const float*)d_in[3];
  const float* W2 = (const float*)d_in[4];
  const float* b2 = (const float*)d_in[5];

  const int IN = 256;
  const int E = in_sizes[1] / 2;
  const int N = in_sizes[0] / IN;
  const int* src = ei;
  const int* dst = ei + E;
  const int nbins = (N + BIN_NODES - 1) >> BIN_SHIFT;
  const int nsup = (N + (1 << SUP_SHIFT) - 1) >> SUP_SHIFT;

  // workspace carve-up (256B aligned)
  char* ws = (char*)d_ws;
  size_t off = 0;
  auto alloc = [&](size_t bytes) -> void* {
    void* p = ws + off;
    off += (bytes + 255) & ~(size_t)255;
    return p;
  };
  int* count = (int*)alloc((size_t)N * 4);
  int* rowptr = (int*)alloc((size_t)(N + 1) * 4);
  float* dis = (float*)alloc((size_t)N * 4);
  int* binCnt = (int*)alloc(MAX_BINS * 4);
  int* binStart = (int*)alloc((MAX_BINS + 1) * 4);
  int* binCursor = (int*)alloc(MAX_BINS * 4);
  int* supCursor = (int*)alloc(NSUP_MAX * 4);
  int* col = (int*)alloc((size_t)E * 4);                // 12.8 MB; written by bin_csr
  unsigned* supbuf = (unsigned*)col;                    // alias: dead before col written
  uint2* out1 = (uint2*)alloc((size_t)N * 64 * 2);      // bf16 layer-1 activations
  size_t big = ((size_t)E * 4 > (size_t)N * 128) ? (size_t)E * 4 : (size_t)N * 128;
  unsigned* binbuf = (unsigned*)alloc(big);             // aliases h (dead before gemm1)
  uint2* h = (uint2*)binbuf;
  ushort_t* wt1 = (ushort_t*)alloc((size_t)2 * 64 * 256 * 2);  // 64 KB split W1
  ushort_t* wt2 = (ushort_t*)alloc((size_t)2 * 64 * 64 * 2);   // 16 KB split W2
  float* outf = (float*)d_out;

  zero_int<<<(nbins + 255) / 256, 256, 0, stream>>>(binCnt, nbins);
  bin_count<<<1024, 256, 0, stream>>>(dst, E, nbins, binCnt);
  bin_scan<<<1, 256, 0, stream>>>(binCnt, nbins, E, binStart, binCursor, supCursor);
  super_fill<<<(E + 2047) / 2048, 256, 0, stream>>>(src, dst, E, nsup, supCursor, supbuf);
  fine_fill<<<nsup * 8, 256, 0, stream>>>(supbuf, binStart, nbins, binCursor, binbuf);
  node_count_dis<<<nbins, 256, 0, stream>>>(binbuf, binStart, N, count, dis);
  bin_csr<<<nbins, 256, 0, stream>>>(binbuf, binStart, count, N, E, rowptr, col);
  wsplit<<<(256 * 64 + 64 * 64 + 255) / 256, 256, 0, stream>>>(W1, W2, wt1, wt2);

  gemm1_mfma<<<(N + 127) / 128, 256, 0, stream>>>(x, wt1, h, N);
  agg_kernel<true><<<(N + 3) / 4, 256, 0, stream>>>(h, rowptr, col, dis, b1, out1, N, 1);
  gemm2_mfma<<<(N + 127) / 128, 256, 0, stream>>>((const ushort_t*)out1, wt2, h, N);
  agg_kernel<false><<<(N + 3) / 4, 256, 0, stream>>>(h, rowptr, col, dis, b2, outf, N, 0);
}